// Round 1
// baseline (444.623 us; speedup 1.0000x reference)
//
#include <hip/hip_runtime.h>
#include <stdint.h>

#define NB 4
#define BS 4096
#define BH 512

typedef __attribute__((ext_vector_type(8))) short bf16x8;
typedef __attribute__((ext_vector_type(4))) float f32x4;

static __device__ __forceinline__ ushort f2bf(float x) {
    union { float f; uint32_t u; } c; c.f = x;
    uint32_t r = c.u + 0x7FFFu + ((c.u >> 16) & 1u);
    return (ushort)(r >> 16);
}

// ---------------------------------------------------------------------------
// Projection GEMM: Y[m,n] = sum_k X[m,k]*W[n,k] + bias[n]
// X fp32 [M,512] row-major, W fp32 [512,512] row-major ([out,in] -> NT gemm)
// TRANSPOSED==0: out bf16 [M,512] row-major (Q,K)
// TRANSPOSED==1: out bf16 vT[b][h][s] = out[(b*512+n)*4096 + s]  (V)
// ---------------------------------------------------------------------------
template<int TRANSPOSED>
__global__ __launch_bounds__(256) void proj_kernel(const float* __restrict__ X,
                                                   const float* __restrict__ W,
                                                   const float* __restrict__ bias,
                                                   ushort* __restrict__ out)
{
    __shared__ ushort As[128 * 32];
    __shared__ ushort Bs[128 * 32];
    const int tid  = threadIdx.x;
    const int lane = tid & 63;
    const int wave = tid >> 6;
    const int wr = wave >> 1, wc = wave & 1;
    const int bi = blockIdx.y, bj = blockIdx.x;

    f32x4 acc[4][4];
    #pragma unroll
    for (int m = 0; m < 4; m++)
        #pragma unroll
        for (int n = 0; n < 4; n++) acc[m][n] = (f32x4)0.0f;

    const int r  = tid >> 1;          // 0..127
    const int kg = (tid & 1) * 16;    // 0 or 16
    const int kq = (lane >> 4) * 8;
    const int fr = lane & 15;

    for (int kt = 0; kt < 512; kt += 32) {
        {   // stage A (fp32 -> bf16)
            const float* src = X + (size_t)(bi * 128 + r) * 512 + kt + kg;
            ushort tmp[16];
            #pragma unroll
            for (int j = 0; j < 4; j++) {
                float4 v = *reinterpret_cast<const float4*>(src + j * 4);
                tmp[j*4+0] = f2bf(v.x); tmp[j*4+1] = f2bf(v.y);
                tmp[j*4+2] = f2bf(v.z); tmp[j*4+3] = f2bf(v.w);
            }
            ushort* dst = &As[r * 32 + kg];
            *reinterpret_cast<uint4*>(dst)     = *reinterpret_cast<const uint4*>(tmp);
            *reinterpret_cast<uint4*>(dst + 8) = *reinterpret_cast<const uint4*>(tmp + 8);
        }
        {   // stage B = W tile (fp32 -> bf16)
            const float* src = W + (size_t)(bj * 128 + r) * 512 + kt + kg;
            ushort tmp[16];
            #pragma unroll
            for (int j = 0; j < 4; j++) {
                float4 v = *reinterpret_cast<const float4*>(src + j * 4);
                tmp[j*4+0] = f2bf(v.x); tmp[j*4+1] = f2bf(v.y);
                tmp[j*4+2] = f2bf(v.z); tmp[j*4+3] = f2bf(v.w);
            }
            ushort* dst = &Bs[r * 32 + kg];
            *reinterpret_cast<uint4*>(dst)     = *reinterpret_cast<const uint4*>(tmp);
            *reinterpret_cast<uint4*>(dst + 8) = *reinterpret_cast<const uint4*>(tmp + 8);
        }
        __syncthreads();

        bf16x8 af[4], bf[4];
        #pragma unroll
        for (int m = 0; m < 4; m++)
            af[m] = *reinterpret_cast<const bf16x8*>(&As[(wr*64 + m*16 + fr) * 32 + kq]);
        #pragma unroll
        for (int n = 0; n < 4; n++)
            bf[n] = *reinterpret_cast<const bf16x8*>(&Bs[(wc*64 + n*16 + fr) * 32 + kq]);
        #pragma unroll
        for (int m = 0; m < 4; m++)
            #pragma unroll
            for (int n = 0; n < 4; n++)
                acc[m][n] = __builtin_amdgcn_mfma_f32_16x16x32_bf16(af[m], bf[n], acc[m][n], 0, 0, 0);
        __syncthreads();
    }

    const int fq = lane >> 4;
    #pragma unroll
    for (int n = 0; n < 4; n++) {
        const int col = bj * 128 + wc * 64 + n * 16 + fr;
        const float bv = bias[col];
        #pragma unroll
        for (int m = 0; m < 4; m++) {
            const int row0 = bi * 128 + wr * 64 + m * 16 + fq * 4;
            if (TRANSPOSED) {
                const int b = row0 >> 12;
                const int s = row0 & 4095;
                ushort4 pk;
                pk.x = f2bf(acc[m][n][0] + bv);
                pk.y = f2bf(acc[m][n][1] + bv);
                pk.z = f2bf(acc[m][n][2] + bv);
                pk.w = f2bf(acc[m][n][3] + bv);
                *reinterpret_cast<ushort4*>(&out[((size_t)b * 512 + col) * 4096 + s]) = pk;
            } else {
                #pragma unroll
                for (int j = 0; j < 4; j++)
                    out[(size_t)(row0 + j) * 512 + col] = f2bf(acc[m][n][j] + bv);
            }
        }
    }
}

// ---------------------------------------------------------------------------
// QK^T: scores[b,i,j] = scale * dot(Q[b,i,:], K[b,j,:]); j>i -> 0
// Q,K bf16 [B*S, 512] row-major. attn fp32 [B,S,S].
// ---------------------------------------------------------------------------
__global__ __launch_bounds__(256) void qk_kernel(const ushort* __restrict__ qb,
                                                 const ushort* __restrict__ kb,
                                                 float* __restrict__ attn)
{
    const int b  = blockIdx.z;
    const int bi = blockIdx.y, bj = blockIdx.x;
    float* aout = attn + (size_t)b * BS * BS;
    const int tid = threadIdx.x;

    if (bj > bi) {  // fully masked tile -> zeros
        const int r  = tid >> 1;
        const int cg = (tid & 1) * 64;
        float4 z = make_float4(0.f, 0.f, 0.f, 0.f);
        float* dst = aout + (size_t)(bi * 128 + r) * BS + bj * 128 + cg;
        #pragma unroll
        for (int j = 0; j < 16; j++) reinterpret_cast<float4*>(dst)[j] = z;
        return;
    }

    __shared__ ushort As[128 * 32];
    __shared__ ushort Bsh[128 * 32];
    const int lane = tid & 63;
    const int wave = tid >> 6;
    const int wr = wave >> 1, wc = wave & 1;

    f32x4 acc[4][4];
    #pragma unroll
    for (int m = 0; m < 4; m++)
        #pragma unroll
        for (int n = 0; n < 4; n++) acc[m][n] = (f32x4)0.0f;

    const int r  = tid >> 1;
    const int kg = (tid & 1) * 16;
    const int kq = (lane >> 4) * 8;
    const int fr = lane & 15;

    const ushort* Qb = qb + (size_t)(b * BS + bi * 128) * 512;
    const ushort* Kb = kb + (size_t)(b * BS + bj * 128) * 512;

    for (int kt = 0; kt < 512; kt += 32) {
        {
            const ushort* src = Qb + (size_t)r * 512 + kt + kg;
            *reinterpret_cast<uint4*>(&As[r * 32 + kg])     = *reinterpret_cast<const uint4*>(src);
            *reinterpret_cast<uint4*>(&As[r * 32 + kg + 8]) = *reinterpret_cast<const uint4*>(src + 8);
        }
        {
            const ushort* src = Kb + (size_t)r * 512 + kt + kg;
            *reinterpret_cast<uint4*>(&Bsh[r * 32 + kg])     = *reinterpret_cast<const uint4*>(src);
            *reinterpret_cast<uint4*>(&Bsh[r * 32 + kg + 8]) = *reinterpret_cast<const uint4*>(src + 8);
        }
        __syncthreads();

        bf16x8 af[4], bf[4];
        #pragma unroll
        for (int m = 0; m < 4; m++)
            af[m] = *reinterpret_cast<const bf16x8*>(&As[(wr*64 + m*16 + fr) * 32 + kq]);
        #pragma unroll
        for (int n = 0; n < 4; n++)
            bf[n] = *reinterpret_cast<const bf16x8*>(&Bsh[(wc*64 + n*16 + fr) * 32 + kq]);
        #pragma unroll
        for (int m = 0; m < 4; m++)
            #pragma unroll
            for (int n = 0; n < 4; n++)
                acc[m][n] = __builtin_amdgcn_mfma_f32_16x16x32_bf16(af[m], bf[n], acc[m][n], 0, 0, 0);
        __syncthreads();
    }

    const float scaling = 0.044194173824159216f;  // 1/sqrt(512)
    const int fq = lane >> 4;
    #pragma unroll
    for (int n = 0; n < 4; n++) {
        const int col = bj * 128 + wc * 64 + n * 16 + fr;
        #pragma unroll
        for (int m = 0; m < 4; m++) {
            const int row0 = bi * 128 + wr * 64 + m * 16 + fq * 4;
            #pragma unroll
            for (int j = 0; j < 4; j++) {
                const int row = row0 + j;
                float v = acc[m][n][j] * scaling;
                if (col > row) v = 0.0f;  // only possible on diagonal tiles
                aout[(size_t)row * BS + col] = v;
            }
        }
    }
}

// ---------------------------------------------------------------------------
// Row softmax over valid (causal) prefix, in place. One block per row.
// ---------------------------------------------------------------------------
__global__ __launch_bounds__(256) void softmax_kernel(float* __restrict__ attn)
{
    __shared__ float row[4096];
    __shared__ float red[8];
    const int rid = blockIdx.x;
    const int b = rid >> 12, i = rid & 4095;
    float* p = attn + (size_t)b * BS * BS + (size_t)i * BS;
    const int len = i + 1;
    const int tid = threadIdx.x;

    float lmax = -3.0e38f;
    for (int j = tid; j < len; j += 256) {
        float v = p[j];
        row[j] = v;
        lmax = fmaxf(lmax, v);
    }
    #pragma unroll
    for (int o = 32; o > 0; o >>= 1) lmax = fmaxf(lmax, __shfl_xor(lmax, o));
    if ((tid & 63) == 0) red[tid >> 6] = lmax;
    __syncthreads();
    const float mx = fmaxf(fmaxf(red[0], red[1]), fmaxf(red[2], red[3]));

    float lsum = 0.0f;
    for (int j = tid; j < len; j += 256) {
        float e = __expf(row[j] - mx);
        row[j] = e;
        lsum += e;
    }
    #pragma unroll
    for (int o = 32; o > 0; o >>= 1) lsum += __shfl_xor(lsum, o);
    if ((tid & 63) == 0) red[4 + (tid >> 6)] = lsum;
    __syncthreads();
    const float inv = 1.0f / (red[4] + red[5] + red[6] + red[7]);

    for (int j = tid; j < len; j += 256) p[j] = row[j] * inv;
}

// ---------------------------------------------------------------------------
// PV: ctx[b,i,h] = sum_j attn[b,i,j] * V[b,j,h], j <= i (rest exact 0)
// attn fp32 (convert on the fly), vT bf16 [b][h][s] (NT gemm).
// ---------------------------------------------------------------------------
__global__ __launch_bounds__(256) void pv_kernel(const float* __restrict__ attn,
                                                 const ushort* __restrict__ vT,
                                                 float* __restrict__ ctx)
{
    __shared__ ushort As[128 * 32];
    __shared__ ushort Bsh[128 * 32];
    const int b  = blockIdx.z;
    const int bi = blockIdx.y, bj = blockIdx.x;  // bj over H/128 = 4
    const int tid  = threadIdx.x;
    const int lane = tid & 63;
    const int wave = tid >> 6;
    const int wr = wave >> 1, wc = wave & 1;

    f32x4 acc[4][4];
    #pragma unroll
    for (int m = 0; m < 4; m++)
        #pragma unroll
        for (int n = 0; n < 4; n++) acc[m][n] = (f32x4)0.0f;

    const int r  = tid >> 1;
    const int kg = (tid & 1) * 16;
    const int kq = (lane >> 4) * 8;
    const int fr = lane & 15;

    const float*  A  = attn + (size_t)b * BS * BS + (size_t)(bi * 128 + r) * BS;
    const ushort* Vt = vT + (size_t)b * 512 * BS + (size_t)(bj * 128 + r) * BS;

    const int kend = (bi + 1) * 128;  // causal: skip k-tiles above the diagonal
    for (int kt = 0; kt < kend; kt += 32) {
        {   // stage attn (fp32 -> bf16)
            const float* src = A + kt + kg;
            ushort tmp[16];
            #pragma unroll
            for (int j = 0; j < 4; j++) {
                float4 v = *reinterpret_cast<const float4*>(src + j * 4);
                tmp[j*4+0] = f2bf(v.x); tmp[j*4+1] = f2bf(v.y);
                tmp[j*4+2] = f2bf(v.z); tmp[j*4+3] = f2bf(v.w);
            }
            ushort* dst = &As[r * 32 + kg];
            *reinterpret_cast<uint4*>(dst)     = *reinterpret_cast<const uint4*>(tmp);
            *reinterpret_cast<uint4*>(dst + 8) = *reinterpret_cast<const uint4*>(tmp + 8);
        }
        {   // stage vT (bf16 direct)
            const ushort* src = Vt + kt + kg;
            *reinterpret_cast<uint4*>(&Bsh[r * 32 + kg])     = *reinterpret_cast<const uint4*>(src);
            *reinterpret_cast<uint4*>(&Bsh[r * 32 + kg + 8]) = *reinterpret_cast<const uint4*>(src + 8);
        }
        __syncthreads();

        bf16x8 af[4], bf[4];
        #pragma unroll
        for (int m = 0; m < 4; m++)
            af[m] = *reinterpret_cast<const bf16x8*>(&As[(wr*64 + m*16 + fr) * 32 + kq]);
        #pragma unroll
        for (int n = 0; n < 4; n++)
            bf[n] = *reinterpret_cast<const bf16x8*>(&Bsh[(wc*64 + n*16 + fr) * 32 + kq]);
        #pragma unroll
        for (int m = 0; m < 4; m++)
            #pragma unroll
            for (int n = 0; n < 4; n++)
                acc[m][n] = __builtin_amdgcn_mfma_f32_16x16x32_bf16(af[m], bf[n], acc[m][n], 0, 0, 0);
        __syncthreads();
    }

    const int fq = lane >> 4;
    float* C = ctx + (size_t)b * BS * 512;
    #pragma unroll
    for (int n = 0; n < 4; n++) {
        const int col = bj * 128 + wc * 64 + n * 16 + fr;
        #pragma unroll
        for (int m = 0; m < 4; m++) {
            const int row0 = bi * 128 + wr * 64 + m * 16 + fq * 4;
            #pragma unroll
            for (int j = 0; j < 4; j++)
                C[(size_t)(row0 + j) * 512 + col] = acc[m][n][j];
        }
    }
}

extern "C" void kernel_launch(void* const* d_in, const int* in_sizes, int n_in,
                              void* d_out, int out_size, void* d_ws, size_t ws_size,
                              hipStream_t stream)
{
    const float* queries = (const float*)d_in[0];
    const float* keys    = (const float*)d_in[1];
    const float* values  = (const float*)d_in[2];
    const float* Wq = (const float*)d_in[3];
    const float* bq = (const float*)d_in[4];
    const float* Wk = (const float*)d_in[5];
    const float* bk = (const float*)d_in[6];
    const float* Wv = (const float*)d_in[7];
    const float* bv = (const float*)d_in[8];

    float* ctx  = (float*)d_out;                         // [B,S,H]
    float* attn = (float*)d_out + (size_t)NB * BS * BH;  // [B,S,S]

    ushort* qb = (ushort*)d_ws;                          // bf16 [B*S, H]
    ushort* kb = qb + (size_t)NB * BS * BH;
    ushort* vT = kb + (size_t)NB * BS * BH;              // bf16 [B][H][S]

    dim3 blk(256);
    dim3 gproj(4, 128);
    proj_kernel<0><<<gproj, blk, 0, stream>>>(queries, Wq, bq, qb);
    proj_kernel<0><<<gproj, blk, 0, stream>>>(keys,    Wk, bk, kb);
    proj_kernel<1><<<gproj, blk, 0, stream>>>(values,  Wv, bv, vT);

    dim3 gqk(BS / 128, BS / 128, NB);
    qk_kernel<<<gqk, blk, 0, stream>>>(qb, kb, attn);

    softmax_kernel<<<dim3(NB * BS), blk, 0, stream>>>(attn);

    dim3 gpv(BH / 128, BS / 128, NB);
    pv_kernel<<<gpv, blk, 0, stream>>>(attn, vT, ctx);
}

// Round 2
// 427.295 us; speedup vs baseline: 1.0406x; 1.0406x over previous
//
#include <hip/hip_runtime.h>
#include <hip/hip_bf16.h>
#include <stdint.h>

#define NB 4
#define BS 4096
#define BH 512

typedef __attribute__((ext_vector_type(8))) short bf16x8;
typedef __attribute__((ext_vector_type(4))) float f32x4;

static __device__ __forceinline__ ushort f2bf(float x) {
    union { float f; uint32_t u; } c; c.f = x;
    uint32_t r = c.u + 0x7FFFu + ((c.u >> 16) & 1u);
    return (ushort)(r >> 16);
}

// async global -> LDS, 16B per lane. dest = wave-uniform base + lane*16.
static __device__ __forceinline__ void gl16(const void* gptr, void* lptr) {
    __builtin_amdgcn_global_load_lds(
        (const __attribute__((address_space(1))) void*)gptr,
        (__attribute__((address_space(3))) void*)lptr, 16, 0, 0);
}

// ---------------------------------------------------------------------------
// Projection GEMM: Y[m,n] = sum_k X[m,k]*W[n,k] + bias[n]
// X fp32 [M,512] row-major, W fp32 [512,512] row-major ([out,in] -> NT gemm)
// TRANSPOSED==0: out bf16 [M,512] row-major (Q,K)
// TRANSPOSED==1: out bf16 vT[b][h][s] = out[(b*512+n)*4096 + s]  (V)
// ---------------------------------------------------------------------------
template<int TRANSPOSED>
__global__ __launch_bounds__(256) void proj_kernel(const float* __restrict__ X,
                                                   const float* __restrict__ W,
                                                   const float* __restrict__ bias,
                                                   ushort* __restrict__ out)
{
    __shared__ ushort As[128 * 32];
    __shared__ ushort Bs[128 * 32];
    const int tid  = threadIdx.x;
    const int lane = tid & 63;
    const int wave = tid >> 6;
    const int wr = wave >> 1, wc = wave & 1;
    const int bi = blockIdx.y, bj = blockIdx.x;

    f32x4 acc[4][4];
    #pragma unroll
    for (int m = 0; m < 4; m++)
        #pragma unroll
        for (int n = 0; n < 4; n++) acc[m][n] = (f32x4)0.0f;

    const int r  = tid >> 1;          // 0..127
    const int kg = (tid & 1) * 16;    // 0 or 16
    const int kq = (lane >> 4) * 8;
    const int fr = lane & 15;

    for (int kt = 0; kt < 512; kt += 32) {
        {   // stage A (fp32 -> bf16)
            const float* src = X + (size_t)(bi * 128 + r) * 512 + kt + kg;
            ushort tmp[16];
            #pragma unroll
            for (int j = 0; j < 4; j++) {
                float4 v = *reinterpret_cast<const float4*>(src + j * 4);
                tmp[j*4+0] = f2bf(v.x); tmp[j*4+1] = f2bf(v.y);
                tmp[j*4+2] = f2bf(v.z); tmp[j*4+3] = f2bf(v.w);
            }
            ushort* dst = &As[r * 32 + kg];
            *reinterpret_cast<uint4*>(dst)     = *reinterpret_cast<const uint4*>(tmp);
            *reinterpret_cast<uint4*>(dst + 8) = *reinterpret_cast<const uint4*>(tmp + 8);
        }
        {   // stage B = W tile (fp32 -> bf16)
            const float* src = W + (size_t)(bj * 128 + r) * 512 + kt + kg;
            ushort tmp[16];
            #pragma unroll
            for (int j = 0; j < 4; j++) {
                float4 v = *reinterpret_cast<const float4*>(src + j * 4);
                tmp[j*4+0] = f2bf(v.x); tmp[j*4+1] = f2bf(v.y);
                tmp[j*4+2] = f2bf(v.z); tmp[j*4+3] = f2bf(v.w);
            }
            ushort* dst = &Bs[r * 32 + kg];
            *reinterpret_cast<uint4*>(dst)     = *reinterpret_cast<const uint4*>(tmp);
            *reinterpret_cast<uint4*>(dst + 8) = *reinterpret_cast<const uint4*>(tmp + 8);
        }
        __syncthreads();

        bf16x8 af[4], bf[4];
        #pragma unroll
        for (int m = 0; m < 4; m++)
            af[m] = *reinterpret_cast<const bf16x8*>(&As[(wr*64 + m*16 + fr) * 32 + kq]);
        #pragma unroll
        for (int n = 0; n < 4; n++)
            bf[n] = *reinterpret_cast<const bf16x8*>(&Bs[(wc*64 + n*16 + fr) * 32 + kq]);
        #pragma unroll
        for (int m = 0; m < 4; m++)
            #pragma unroll
            for (int n = 0; n < 4; n++)
                acc[m][n] = __builtin_amdgcn_mfma_f32_16x16x32_bf16(af[m], bf[n], acc[m][n], 0, 0, 0);
        __syncthreads();
    }

    const int fq = lane >> 4;
    #pragma unroll
    for (int n = 0; n < 4; n++) {
        const int col = bj * 128 + wc * 64 + n * 16 + fr;
        const float bv = bias[col];
        #pragma unroll
        for (int m = 0; m < 4; m++) {
            const int row0 = bi * 128 + wr * 64 + m * 16 + fq * 4;
            if (TRANSPOSED) {
                const int b = row0 >> 12;
                const int s = row0 & 4095;
                ushort4 pk;
                pk.x = f2bf(acc[m][n][0] + bv);
                pk.y = f2bf(acc[m][n][1] + bv);
                pk.z = f2bf(acc[m][n][2] + bv);
                pk.w = f2bf(acc[m][n][3] + bv);
                *reinterpret_cast<ushort4*>(&out[((size_t)b * 512 + col) * 4096 + s]) = pk;
            } else {
                #pragma unroll
                for (int j = 0; j < 4; j++)
                    out[(size_t)(row0 + j) * 512 + col] = f2bf(acc[m][n][j] + bv);
            }
        }
    }
}

// ---------------------------------------------------------------------------
// QK^T: scores[b,i,j] = scale * dot(Q[b,i,:], K[b,j,:]); j>i -> 0
// Q,K bf16 [B*S, 512] row-major. attn fp32 [B,S,S].
// global_load_lds staging (m97 structure) + XCD-swizzled block ids.
// ---------------------------------------------------------------------------
__global__ __launch_bounds__(256) void qk_kernel(const ushort* __restrict__ qb,
                                                 const ushort* __restrict__ kb,
                                                 float* __restrict__ attn)
{
    // XCD-aware bijective swizzle: nwg = 4096 (divisible by 8)
    const int flat = blockIdx.x + (blockIdx.y << 5) + (blockIdx.z << 10);
    const int s    = (flat & 7) * 512 + (flat >> 3);
    const int bj = s & 31, bi = (s >> 5) & 31, b = s >> 10;

    float* aout = attn + (size_t)b * BS * BS;
    const int tid = threadIdx.x;

    if (bj > bi) {  // fully masked tile -> zeros
        const int r  = tid >> 1;
        const int cg = (tid & 1) * 64;
        float4 z = make_float4(0.f, 0.f, 0.f, 0.f);
        float* dst = aout + (size_t)(bi * 128 + r) * BS + bj * 128 + cg;
        #pragma unroll
        for (int j = 0; j < 16; j++) reinterpret_cast<float4*>(dst)[j] = z;
        return;
    }

    __shared__ ushort As[128 * 32];
    __shared__ ushort Bsh[128 * 32];
    const int lane = tid & 63;
    const int wave = tid >> 6;
    const int wr = wave >> 1, wc = wave & 1;

    f32x4 acc[4][4];
    #pragma unroll
    for (int m = 0; m < 4; m++)
        #pragma unroll
        for (int n = 0; n < 4; n++) acc[m][n] = (f32x4)0.0f;

    const ushort* Qb = qb + (size_t)(b * BS + bi * 128) * 512;
    const ushort* Kb = kb + (size_t)(b * BS + bj * 128) * 512;

    // gload chunk assignment: wave handles chunks {2w, 2w+1} of A and B.
    // chunk c = rows [c*16, c*16+16), lane -> row c*16 + (lane>>2), col (lane&3)*8
    const int c0 = wave * 2, c1 = wave * 2 + 1;
    const int glr = lane >> 2;
    const int glc = (lane & 3) * 8;
    const ushort* ga0 = Qb + (size_t)(c0 * 16 + glr) * 512 + glc;
    const ushort* ga1 = Qb + (size_t)(c1 * 16 + glr) * 512 + glc;
    const ushort* gb0 = Kb + (size_t)(c0 * 16 + glr) * 512 + glc;
    const ushort* gb1 = Kb + (size_t)(c1 * 16 + glr) * 512 + glc;
    ushort* la0 = &As[c0 * 512];
    ushort* la1 = &As[c1 * 512];
    ushort* lb0 = &Bsh[c0 * 512];
    ushort* lb1 = &Bsh[c1 * 512];

    const int kq = (lane >> 4) * 8;
    const int fr = lane & 15;

    for (int kt = 0; kt < 512; kt += 32) {
        gl16(ga0 + kt, la0);
        gl16(ga1 + kt, la1);
        gl16(gb0 + kt, lb0);
        gl16(gb1 + kt, lb1);
        __syncthreads();

        bf16x8 af[4], bf[4];
        #pragma unroll
        for (int m = 0; m < 4; m++)
            af[m] = *reinterpret_cast<const bf16x8*>(&As[(wr*64 + m*16 + fr) * 32 + kq]);
        #pragma unroll
        for (int n = 0; n < 4; n++)
            bf[n] = *reinterpret_cast<const bf16x8*>(&Bsh[(wc*64 + n*16 + fr) * 32 + kq]);
        #pragma unroll
        for (int m = 0; m < 4; m++)
            #pragma unroll
            for (int n = 0; n < 4; n++)
                acc[m][n] = __builtin_amdgcn_mfma_f32_16x16x32_bf16(af[m], bf[n], acc[m][n], 0, 0, 0);
        __syncthreads();
    }

    const float scaling = 0.044194173824159216f;  // 1/sqrt(512)
    const int fq = lane >> 4;
    #pragma unroll
    for (int n = 0; n < 4; n++) {
        const int col = bj * 128 + wc * 64 + n * 16 + fr;
        #pragma unroll
        for (int m = 0; m < 4; m++) {
            const int row0 = bi * 128 + wr * 64 + m * 16 + fq * 4;
            #pragma unroll
            for (int j = 0; j < 4; j++) {
                const int row = row0 + j;
                float v = acc[m][n][j] * scaling;
                if (col > row) v = 0.0f;  // only possible on diagonal tiles
                aout[(size_t)row * BS + col] = v;
            }
        }
    }
}

// ---------------------------------------------------------------------------
// Row softmax over valid (causal) prefix, in place. One block per row.
// ---------------------------------------------------------------------------
__global__ __launch_bounds__(256) void softmax_kernel(float* __restrict__ attn)
{
    __shared__ float row[4096];
    __shared__ float red[8];
    const int rid = blockIdx.x;
    const int b = rid >> 12, i = rid & 4095;
    float* p = attn + (size_t)b * BS * BS + (size_t)i * BS;
    const int len = i + 1;
    const int tid = threadIdx.x;

    float lmax = -3.0e38f;
    for (int j = tid; j < len; j += 256) {
        float v = p[j];
        row[j] = v;
        lmax = fmaxf(lmax, v);
    }
    #pragma unroll
    for (int o = 32; o > 0; o >>= 1) lmax = fmaxf(lmax, __shfl_xor(lmax, o));
    if ((tid & 63) == 0) red[tid >> 6] = lmax;
    __syncthreads();
    const float mx = fmaxf(fmaxf(red[0], red[1]), fmaxf(red[2], red[3]));

    float lsum = 0.0f;
    for (int j = tid; j < len; j += 256) {
        float e = __expf(row[j] - mx);
        row[j] = e;
        lsum += e;
    }
    #pragma unroll
    for (int o = 32; o > 0; o >>= 1) lsum += __shfl_xor(lsum, o);
    if ((tid & 63) == 0) red[4 + (tid >> 6)] = lsum;
    __syncthreads();
    const float inv = 1.0f / (red[4] + red[5] + red[6] + red[7]);

    for (int j = tid; j < len; j += 256) p[j] = row[j] * inv;
}

// ---------------------------------------------------------------------------
// PV: ctx[b,i,h] = sum_j attn[b,i,j] * V[b,j,h], j <= i (rest exact 0)
// attn fp32 staged via global_load_lds with granule XOR-swizzle (rule #21:
// linear LDS dest + inverse-swizzled SOURCE + swizzled READ), converted to
// bf16 on the register path. vT bf16 via linear global_load_lds.
// ---------------------------------------------------------------------------
__global__ __launch_bounds__(256) void pv_kernel(const float* __restrict__ attn,
                                                 const ushort* __restrict__ vT,
                                                 float* __restrict__ ctx)
{
    // XCD-aware bijective swizzle: nwg = 512
    const int flat = blockIdx.x + (blockIdx.y << 2) + (blockIdx.z << 7);
    const int s    = (flat & 7) * 64 + (flat >> 3);
    const int bj = s & 3, bi = (s >> 2) & 31, b = s >> 7;

    __shared__ float  Asf[128 * 32];   // 16 KB, fp32 attn tile
    __shared__ ushort Bsh[128 * 32];   // 8 KB, bf16 vT tile
    const int tid  = threadIdx.x;
    const int lane = tid & 63;
    const int wave = tid >> 6;
    const int wr = wave >> 1, wc = wave & 1;

    f32x4 acc[4][4];
    #pragma unroll
    for (int m = 0; m < 4; m++)
        #pragma unroll
        for (int n = 0; n < 4; n++) acc[m][n] = (f32x4)0.0f;

    const float*  Ab = attn + (size_t)b * BS * BS;
    const ushort* Vb = vT + (size_t)b * 512 * BS;

    // A (fp32): 16 chunks of 1KB, wave handles 4w..4w+3.
    // chunk c = rows [c*8, c*8+8); lane -> row c*8 + (lane>>3), granule lane&7.
    // inverse-swizzled source granule: gsrc = (lane&7) ^ ((lane>>3)&7)
    const int arow_in = lane >> 3;                       // 0..7 within chunk
    const int gsrc    = (lane & 7) ^ (arow_in & 7);      // granule (16B = 4 floats)
    const float* gA[4];
    float* lA[4];
    #pragma unroll
    for (int i = 0; i < 4; i++) {
        const int c = wave * 4 + i;
        gA[i] = Ab + (size_t)(bi * 128 + c * 8 + arow_in) * BS + gsrc * 4;
        lA[i] = &Asf[c * 256];
    }
    // B (bf16 vT): 8 chunks of 1KB, wave handles {2w, 2w+1}.
    const int c0 = wave * 2, c1 = wave * 2 + 1;
    const int glr = lane >> 2;
    const int glc = (lane & 3) * 8;
    const ushort* gB0 = Vb + (size_t)(bj * 128 + c0 * 16 + glr) * BS + glc;
    const ushort* gB1 = Vb + (size_t)(bj * 128 + c1 * 16 + glr) * BS + glc;
    ushort* lB0 = &Bsh[c0 * 512];
    ushort* lB1 = &Bsh[c1 * 512];

    const int kq = (lane >> 4) * 8;    // element offset in K (bf16 path)
    const int fr = lane & 15;
    const int cg0 = (lane >> 4) * 2;   // fp32 granule pair for the A frag

    const int kend = (bi + 1) * 128;   // causal: skip k-tiles above the diagonal
    for (int kt = 0; kt < kend; kt += 32) {
        #pragma unroll
        for (int i = 0; i < 4; i++) gl16(gA[i] + kt, lA[i]);
        gl16(gB0 + kt, lB0);
        gl16(gB1 + kt, lB1);
        __syncthreads();

        bf16x8 af[4], bf[4];
        #pragma unroll
        for (int m = 0; m < 4; m++) {
            const int row = wr * 64 + m * 16 + fr;
            const int r7  = row & 7;
            float4 a0 = *reinterpret_cast<const float4*>(&Asf[row * 32 + ((cg0    ) ^ r7) * 4]);
            float4 a1 = *reinterpret_cast<const float4*>(&Asf[row * 32 + ((cg0 + 1) ^ r7) * 4]);
            bf16x8 t;
            t[0] = (short)f2bf(a0.x); t[1] = (short)f2bf(a0.y);
            t[2] = (short)f2bf(a0.z); t[3] = (short)f2bf(a0.w);
            t[4] = (short)f2bf(a1.x); t[5] = (short)f2bf(a1.y);
            t[6] = (short)f2bf(a1.z); t[7] = (short)f2bf(a1.w);
            af[m] = t;
        }
        #pragma unroll
        for (int n = 0; n < 4; n++)
            bf[n] = *reinterpret_cast<const bf16x8*>(&Bsh[(wc*64 + n*16 + fr) * 32 + kq]);
        #pragma unroll
        for (int m = 0; m < 4; m++)
            #pragma unroll
            for (int n = 0; n < 4; n++)
                acc[m][n] = __builtin_amdgcn_mfma_f32_16x16x32_bf16(af[m], bf[n], acc[m][n], 0, 0, 0);
        __syncthreads();
    }

    const int fq = lane >> 4;
    float* C = ctx + (size_t)b * BS * 512;
    #pragma unroll
    for (int n = 0; n < 4; n++) {
        const int col = bj * 128 + wc * 64 + n * 16 + fr;
        #pragma unroll
        for (int m = 0; m < 4; m++) {
            const int row0 = bi * 128 + wr * 64 + m * 16 + fq * 4;
            #pragma unroll
            for (int j = 0; j < 4; j++)
                C[(size_t)(row0 + j) * 512 + col] = acc[m][n][j];
        }
    }
}

extern "C" void kernel_launch(void* const* d_in, const int* in_sizes, int n_in,
                              void* d_out, int out_size, void* d_ws, size_t ws_size,
                              hipStream_t stream)
{
    const float* queries = (const float*)d_in[0];
    const float* keys    = (const float*)d_in[1];
    const float* values  = (const float*)d_in[2];
    const float* Wq = (const float*)d_in[3];
    const float* bq = (const float*)d_in[4];
    const float* Wk = (const float*)d_in[5];
    const float* bk = (const float*)d_in[6];
    const float* Wv = (const float*)d_in[7];
    const float* bv = (const float*)d_in[8];

    float* ctx  = (float*)d_out;                         // [B,S,H]
    float* attn = (float*)d_out + (size_t)NB * BS * BH;  // [B,S,S]

    ushort* qb = (ushort*)d_ws;                          // bf16 [B*S, H]
    ushort* kb = qb + (size_t)NB * BS * BH;
    ushort* vT = kb + (size_t)NB * BS * BH;              // bf16 [B][H][S]

    dim3 blk(256);
    dim3 gproj(4, 128);
    proj_kernel<0><<<gproj, blk, 0, stream>>>(queries, Wq, bq, qb);
    proj_kernel<0><<<gproj, blk, 0, stream>>>(keys,    Wk, bk, kb);
    proj_kernel<1><<<gproj, blk, 0, stream>>>(values,  Wv, bv, vT);

    dim3 gqk(BS / 128, BS / 128, NB);
    qk_kernel<<<gqk, blk, 0, stream>>>(qb, kb, attn);

    softmax_kernel<<<dim3(NB * BS), blk, 0, stream>>>(attn);

    dim3 gpv(BH / 128, BS / 128, NB);
    pv_kernel<<<gpv, blk, 0, stream>>>(attn, vT, ctx);
}